// Round 21
// baseline (267.768 us; speedup 1.0000x reference)
//
#include <hip/hip_runtime.h>

#define CIN  512
#define HDIM 16
#define CODIM 40
#define BINSZ 256      // nodes per bin
#define BSHIFT 8
#define NBMAX 512      // max bins (N <= 131072)
#define EB 4096        // edges per binning block (16/thread at 256 threads)
#define CAP 9216       // padded per-bin capacity (mean 8184 + 11 sigma)
#define WSTR 36        // gemm1: uints per 4-k group (32 data + 4 pad; 36 % 32 == 4)

__device__ __forceinline__ void fma4(float4& a, float s, float4 b) {
  a.x = fmaf(s, b.x, a.x);
  a.y = fmaf(s, b.y, a.y);
  a.z = fmaf(s, b.z, a.z);
  a.w = fmaf(s, b.w, a.w);
}

__device__ __forceinline__ float4 red4(float4 v) {
  v.x += __shfl_xor(v.x, 1); v.y += __shfl_xor(v.y, 1);
  v.z += __shfl_xor(v.z, 1); v.w += __shfl_xor(v.w, 1);
  v.x += __shfl_xor(v.x, 2); v.y += __shfl_xor(v.y, 2);
  v.z += __shfl_xor(v.z, 2); v.w += __shfl_xor(v.w, 2);
  return v;
}

__device__ __forceinline__ float4 shx4(float4 v, int m) {
  return make_float4(__shfl_xor(v.x, m), __shfl_xor(v.y, m),
                     __shfl_xor(v.z, m), __shfl_xor(v.w, m));
}

// bf16 (stored as ushort/uint) helpers: f32 accumulate, bf16 storage
__device__ __forceinline__ float4 bf4(ushort4 u) {
  return make_float4(__uint_as_float((unsigned)u.x << 16),
                     __uint_as_float((unsigned)u.y << 16),
                     __uint_as_float((unsigned)u.z << 16),
                     __uint_as_float((unsigned)u.w << 16));
}
__device__ __forceinline__ unsigned short f2bf(float f) {
  unsigned u = __float_as_uint(f);
  return (unsigned short)((u + 0x7FFFu + ((u >> 16) & 1u)) >> 16);
}
__device__ __forceinline__ ushort4 pk4(float4 v) {
  ushort4 r;
  r.x = f2bf(v.x); r.y = f2bf(v.y); r.z = f2bf(v.z); r.w = f2bf(v.w);
  return r;
}
__device__ __forceinline__ unsigned pk2(float lo, float hi) {
  return (unsigned)f2bf(lo) | ((unsigned)f2bf(hi) << 16);
}
__device__ __forceinline__ float bl(unsigned u) { return __uint_as_float(u << 16); }
__device__ __forceinline__ float bh(unsigned u) { return __uint_as_float(u & 0xFFFF0000u); }

__global__ void k_zero(int* __restrict__ p, int n) {
  int i = blockIdx.x * 256 + threadIdx.x;
  if (i < n) p[i] = 0;
}

// single-pass binning into fixed-capacity padded bins; int4 vectorized loads.
__global__ __launch_bounds__(256) void k_binB(const int* __restrict__ src,
                                              const int* __restrict__ dst,
                                              const float* __restrict__ w,
                                              int* __restrict__ cursor,
                                              uint2* __restrict__ binned, int E) {
  __shared__ int hist[NBMAX];
  __shared__ int base[NBMAX];
  int t = threadIdx.x;
  for (int i = t; i < NBMAX; i += 256) hist[i] = 0;
  __syncthreads();
  int beg = blockIdx.x * EB, end = min(E, beg + EB);
  int dbuf[16];
  #pragma unroll
  for (int j = 0; j < 4; ++j) {
    int e = beg + t * 4 + j * 1024;
    if (e + 3 < end) {
      int4 d4 = *(const int4*)(dst + e);
      dbuf[4 * j + 0] = d4.x; dbuf[4 * j + 1] = d4.y;
      dbuf[4 * j + 2] = d4.z; dbuf[4 * j + 3] = d4.w;
      atomicAdd(&hist[d4.x >> BSHIFT], 1);
      atomicAdd(&hist[d4.y >> BSHIFT], 1);
      atomicAdd(&hist[d4.z >> BSHIFT], 1);
      atomicAdd(&hist[d4.w >> BSHIFT], 1);
    } else {
      #pragma unroll
      for (int k = 0; k < 4; ++k) {
        int ee = e + k;
        int d = (ee < end) ? dst[ee] : -1;
        dbuf[4 * j + k] = d;
        if (d >= 0) atomicAdd(&hist[d >> BSHIFT], 1);
      }
    }
  }
  __syncthreads();
  for (int i = t; i < NBMAX; i += 256) {
    int h = hist[i];
    base[i] = h ? (i * CAP + atomicAdd(&cursor[i], h)) : 0;
  }
  __syncthreads();
  #pragma unroll
  for (int j = 0; j < 4; ++j) {
    int e = beg + t * 4 + j * 1024;
    if (e + 3 < end) {
      int4   s4 = *(const int4*)(src + e);
      float4 w4 = *(const float4*)(w + e);
      int ss[4] = {s4.x, s4.y, s4.z, s4.w};
      float ww[4] = {w4.x, w4.y, w4.z, w4.w};
      #pragma unroll
      for (int k = 0; k < 4; ++k) {
        int d = dbuf[4 * j + k];
        int b = d >> BSHIFT;
        int pos = atomicAdd(&base[b], 1);
        binned[pos] = make_uint2((unsigned)ss[k] | ((unsigned)(d & (BINSZ - 1)) << 17),
                                 __float_as_uint(ww[k]));
      }
    } else {
      #pragma unroll
      for (int k = 0; k < 4; ++k) {
        int ee = e + k;
        int d = dbuf[4 * j + k];
        if (d >= 0) {
          int b = d >> BSHIFT;
          int pos = atomicAdd(&base[b], 1);
          binned[pos] = make_uint2((unsigned)src[ee] | ((unsigned)(d & (BINSZ - 1)) << 17),
                                   __float_as_uint(w[ee]));
        }
      }
    }
  }
}

// scan bin counts -> compact csr offsets (cursor holds counts after binB)
__global__ __launch_bounds__(256) void k_scanBins(
    const int* __restrict__ cnt, int* __restrict__ binoff,
    int* __restrict__ rowptr, int NB, int N) {
  __shared__ int ts[256];
  int t = threadIdx.x;
  int c0 = (2 * t     < NB) ? cnt[2 * t]     : 0;
  int c1 = (2 * t + 1 < NB) ? cnt[2 * t + 1] : 0;
  int s = c0 + c1;
  ts[t] = s;
  __syncthreads();
  #pragma unroll
  for (int off = 1; off < 256; off <<= 1) {
    int v = (t >= off) ? ts[t - off] : 0;
    __syncthreads();
    ts[t] += v;
    __syncthreads();
  }
  int ex = ts[t] - s;
  if (2 * t     < NB) binoff[2 * t]     = ex;
  if (2 * t + 1 < NB) binoff[2 * t + 1] = ex + c0;
  if (t == 255) { binoff[NB] = ts[255]; rowptr[N] = ts[255]; }
}

// per-bin counting sort: padded binned -> compact node-sorted csr + rowptr + dis.
// uint4 paired loads; wave-shfl scan over the 256-entry hist.
__global__ __launch_bounds__(1024) void k_csrbin(
    const int* __restrict__ binoff, const uint2* __restrict__ binned,
    int* __restrict__ rowptr, int2* __restrict__ csr,
    float* __restrict__ dis, int N) {
  __shared__ int   hist[BINSZ];
  __shared__ int   loff[BINSZ];
  __shared__ int   rank[BINSZ];
  __shared__ float dsum[BINSZ];
  __shared__ int   wsum[4];
  int t = threadIdx.x, b = blockIdx.x;
  if (t < BINSZ) { hist[t] = 0; rank[t] = 0; dsum[t] = 1.0f; }  // self-loop deg = 1
  __syncthreads();
  int cbeg = binoff[b], cnt = binoff[b + 1] - cbeg;
  size_t pbeg = (size_t)b * CAP;
  uint4 eb2[5];   // 5 pairs = 10 edges/thread; 10240 >= CAP
  #pragma unroll
  for (int j = 0; j < 5; ++j) {
    int p = t + j * 1024;
    int i0 = p * 2;
    if (i0 + 1 < cnt) {
      uint4 E2 = *(const uint4*)(binned + pbeg + i0);
      eb2[j] = E2;
      int dl0 = E2.x >> 17, dl1 = E2.z >> 17;
      atomicAdd(&hist[dl0], 1);
      atomicAdd(&dsum[dl0], __uint_as_float(E2.y));
      atomicAdd(&hist[dl1], 1);
      atomicAdd(&dsum[dl1], __uint_as_float(E2.w));
    } else if (i0 < cnt) {
      uint2 e = binned[pbeg + i0];
      eb2[j].x = e.x; eb2[j].y = e.y;
      int dl = e.x >> 17;
      atomicAdd(&hist[dl], 1);
      atomicAdd(&dsum[dl], __uint_as_float(e.y));
    }
  }
  __syncthreads();
  // wave-level inclusive scan over 256 entries (waves 0-3), combine via wsum
  int h = 0, inc = 0;
  if (t < BINSZ) {
    h = hist[t];
    inc = h;
    #pragma unroll
    for (int off = 1; off < 64; off <<= 1) {
      int v = __shfl_up(inc, off);
      if ((t & 63) >= off) inc += v;
    }
    if ((t & 63) == 63) wsum[t >> 6] = inc;
  }
  __syncthreads();
  if (t < BINSZ) {
    int wid = t >> 6;
    int wadd = 0;
    #pragma unroll
    for (int wv = 0; wv < 3; ++wv) if (wv < wid) wadd += wsum[wv];
    int ex = inc - h + wadd;
    int n = b * BINSZ + t;
    if (n < N) {
      rowptr[n] = cbeg + ex;
      dis[n] = rsqrtf(dsum[t]);
    }
    loff[t] = ex;
  }
  __syncthreads();
  #pragma unroll
  for (int j = 0; j < 5; ++j) {
    int p = t + j * 1024;
    int i0 = p * 2;
    if (i0 < cnt) {
      unsigned ex = eb2[j].x, ey = eb2[j].y;
      int dl = ex >> 17;
      int r = atomicAdd(&rank[dl], 1);
      csr[cbeg + loff[dl] + r] = make_int2((int)(ex & 0x1FFFFu), (int)ey);
    }
    if (i0 + 1 < cnt) {
      unsigned ez = eb2[j].z, ew = eb2[j].w;
      int dl = ez >> 17;
      int r = atomicAdd(&rank[dl], 1);
      csr[cbeg + loff[dl] + r] = make_int2((int)(ez & 0x1FFFFu), (int)ew);
    }
  }
}

// 16 bf16-pair FMAs for TWO nodes sharing the same weights
__device__ __forceinline__ void dot16x2(
    float4& a0, float4& a1, float4& a2, float4& a3,
    float4& b0, float4& b1, float4& b2, float4& b3,
    uint4 U0, uint4 U1, float sa, float sb) {
  float w;
  w = bl(U0.x); a0.x = fmaf(sa, w, a0.x); b0.x = fmaf(sb, w, b0.x);
  w = bh(U0.x); a0.y = fmaf(sa, w, a0.y); b0.y = fmaf(sb, w, b0.y);
  w = bl(U0.y); a0.z = fmaf(sa, w, a0.z); b0.z = fmaf(sb, w, b0.z);
  w = bh(U0.y); a0.w = fmaf(sa, w, a0.w); b0.w = fmaf(sb, w, b0.w);
  w = bl(U0.z); a1.x = fmaf(sa, w, a1.x); b1.x = fmaf(sb, w, b1.x);
  w = bh(U0.z); a1.y = fmaf(sa, w, a1.y); b1.y = fmaf(sb, w, b1.y);
  w = bl(U0.w); a1.z = fmaf(sa, w, a1.z); b1.z = fmaf(sb, w, b1.z);
  w = bh(U0.w); a1.w = fmaf(sa, w, a1.w); b1.w = fmaf(sb, w, b1.w);
  w = bl(U1.x); a2.x = fmaf(sa, w, a2.x); b2.x = fmaf(sb, w, b2.x);
  w = bh(U1.x); a2.y = fmaf(sa, w, a2.y); b2.y = fmaf(sb, w, b2.y);
  w = bl(U1.y); a2.z = fmaf(sa, w, a2.z); b2.z = fmaf(sb, w, b2.z);
  w = bh(U1.y); a2.w = fmaf(sa, w, a2.w); b2.w = fmaf(sb, w, b2.w);
  w = bl(U1.z); a3.x = fmaf(sa, w, a3.x); b3.x = fmaf(sb, w, b3.x);
  w = bh(U1.z); a3.y = fmaf(sa, w, a3.y); b3.y = fmaf(sb, w, b3.y);
  w = bl(U1.w); a3.z = fmaf(sa, w, a3.z); b3.z = fmaf(sb, w, b3.z);
  w = bh(U1.w); a3.w = fmaf(sa, w, a3.w); b3.w = fmaf(sb, w, b3.w);
}

// y1[n][:] = bf16( dis[n] * (x[n][:] @ W1) )
// v6: 4 lanes/node, 2 nodes/lane, bf16 LDS (18.4 KB) -> W reads shared, 0.8 GB LDS traffic.
__global__ __launch_bounds__(256, 4) void k_gemm1(
    const float* __restrict__ x, const float* __restrict__ W1,
    const float* __restrict__ dis, unsigned short* __restrict__ y1, int N) {
  __shared__ unsigned w1s[128 * WSTR];  // 18.4 KB
  int t = threadIdx.x;
  const float4* W14 = (const float4*)W1;  // 2048 float4
  for (int lin = t; lin < 2048; lin += 256) {
    float4 v = W14[lin];
    int g = lin >> 4, f = lin & 15;
    unsigned* p = w1s + g * WSTR + (f >> 2) * 8 + (f & 3) * 2;
    p[0] = pk2(v.x, v.y);
    p[1] = pk2(v.z, v.w);
  }
  __syncthreads();

  int quad = t >> 2;
  int q = t & 3;
  int n0 = blockIdx.x * 128 + quad * 2;
  if (n0 >= N) return;
  bool v1 = (n0 + 1) < N;

  const float4* xA = (const float4*)x + (size_t)n0 * (CIN / 4);
  const float4* xB = xA + (CIN / 4);
  float4 z4 = make_float4(0.f, 0.f, 0.f, 0.f);
  float4 a0 = z4, a1 = z4, a2 = z4, a3 = z4;
  float4 b0 = z4, b1 = z4, b2 = z4, b3 = z4;

  #pragma unroll 2
  for (int kk = 0; kk < 32; ++kk) {
    float4 xa = xA[kk * 4 + q];
    float4 xb = v1 ? xB[kk * 4 + q] : z4;
    const uint4* wr = (const uint4*)(w1s + (kk * 4 + q) * WSTR);
    dot16x2(a0, a1, a2, a3, b0, b1, b2, b3, wr[0], wr[1], xa.x, xb.x);
    dot16x2(a0, a1, a2, a3, b0, b1, b2, b3, wr[2], wr[3], xa.y, xb.y);
    dot16x2(a0, a1, a2, a3, b0, b1, b2, b3, wr[4], wr[5], xa.z, xb.z);
    dot16x2(a0, a1, a2, a3, b0, b1, b2, b3, wr[6], wr[7], xa.w, xb.w);
  }
  a0 = red4(a0); a1 = red4(a1); a2 = red4(a2); a3 = red4(a3);
  b0 = red4(b0); b1 = red4(b1); b2 = red4(b2); b3 = red4(b3);

  float dA = dis[n0];
  float4 sA = (q == 0) ? a0 : (q == 1) ? a1 : (q == 2) ? a2 : a3;
  sA.x *= dA; sA.y *= dA; sA.z *= dA; sA.w *= dA;
  ((ushort4*)y1)[(size_t)n0 * 4 + q] = pk4(sA);
  if (v1) {
    float dB = dis[n0 + 1];
    float4 sB = (q == 0) ? b0 : (q == 1) ? b1 : (q == 2) ? b2 : b3;
    sB.x *= dB; sB.y *= dB; sB.z *= dB; sB.w *= dB;
    ((ushort4*)y1)[(size_t)(n0 + 1) * 4 + q] = pk4(sB);
  }
}

// 8-deep unrolled row gather-accumulate over bf16 table
__device__ __forceinline__ float4 rowAccB(const int2* __restrict__ csr,
                                          const ushort4* __restrict__ v4,
                                          float4 s0, int beg, int end, int q) {
  float4 s1 = make_float4(0.f, 0.f, 0.f, 0.f), s2 = s1, s3 = s1;
  int i = beg;
  for (; i + 7 < end; i += 8) {
    int2 e0 = csr[i],     e1 = csr[i + 1], e2 = csr[i + 2], e3 = csr[i + 3];
    int2 e4 = csr[i + 4], e5 = csr[i + 5], e6 = csr[i + 6], e7 = csr[i + 7];
    ushort4 u0 = v4[(size_t)e0.x * 4 + q];
    ushort4 u1 = v4[(size_t)e1.x * 4 + q];
    ushort4 u2 = v4[(size_t)e2.x * 4 + q];
    ushort4 u3 = v4[(size_t)e3.x * 4 + q];
    ushort4 u4 = v4[(size_t)e4.x * 4 + q];
    ushort4 u5 = v4[(size_t)e5.x * 4 + q];
    ushort4 u6 = v4[(size_t)e6.x * 4 + q];
    ushort4 u7 = v4[(size_t)e7.x * 4 + q];
    fma4(s0, __int_as_float(e0.y), bf4(u0));
    fma4(s1, __int_as_float(e1.y), bf4(u1));
    fma4(s2, __int_as_float(e2.y), bf4(u2));
    fma4(s3, __int_as_float(e3.y), bf4(u3));
    fma4(s0, __int_as_float(e4.y), bf4(u4));
    fma4(s1, __int_as_float(e5.y), bf4(u5));
    fma4(s2, __int_as_float(e6.y), bf4(u6));
    fma4(s3, __int_as_float(e7.y), bf4(u7));
  }
  for (; i < end; ++i) {
    int2 e = csr[i];
    fma4(s0, __int_as_float(e.y), bf4(v4[(size_t)e.x * 4 + q]));
  }
  s0.x += s1.x + s2.x + s3.x;
  s0.y += s1.y + s2.y + s3.y;
  s0.z += s1.z + s2.z + s3.z;
  s0.w += s1.w + s2.w + s3.w;
  return s0;
}

// aggregate + z epilogue (bf16 in, bf16 out)
__global__ __launch_bounds__(256) void k_aggZ(
    const int* __restrict__ rowptr, const int2* __restrict__ csr,
    const unsigned short* __restrict__ vals, unsigned short* __restrict__ zb,
    const float* __restrict__ dis, const float* __restrict__ b1, int N) {
  int t = threadIdx.x;
  int node = blockIdx.x * 64 + (t >> 2);
  int q = t & 3;
  if (node >= N) return;
  const ushort4* v4 = (const ushort4*)vals;
  float4 a = rowAccB(csr, v4, bf4(v4[(size_t)node * 4 + q]),
                     rowptr[node], rowptr[node + 1], q);
  float d = dis[node];
  float4 bb = ((const float4*)b1)[q];
  float4 z;
  z.x = d * fmaxf(fmaf(d, a.x, bb.x), 0.f);
  z.y = d * fmaxf(fmaf(d, a.y, bb.y), 0.f);
  z.z = d * fmaxf(fmaf(d, a.z, bb.z), 0.f);
  z.w = d * fmaxf(fmaf(d, a.w, bb.w), 0.f);
  ((ushort4*)zb)[(size_t)node * 4 + q] = pk4(z);
}

// aggregate + final epilogue (bf16 in, W2 matmul + log_softmax, f32 out)
__global__ __launch_bounds__(256) void k_aggF(
    const int* __restrict__ rowptr, const int2* __restrict__ csr,
    const unsigned short* __restrict__ vals, float* __restrict__ out,
    const float* __restrict__ dis, const float* __restrict__ W2,
    const float* __restrict__ b2, int N) {
  __shared__ float w2s[HDIM * CODIM + CODIM];
  int t = threadIdx.x;
  for (int i = t; i < HDIM * CODIM; i += 256) w2s[i] = W2[i];
  if (t < CODIM) w2s[HDIM * CODIM + t] = b2[t];
  __syncthreads();

  int node = blockIdx.x * 64 + (t >> 2);
  int q = t & 3;
  if (node >= N) return;
  const ushort4* v4 = (const ushort4*)vals;
  float4 a = rowAccB(csr, v4, bf4(v4[(size_t)node * 4 + q]),
                     rowptr[node], rowptr[node + 1], q);
  float d = dis[node];
  a.x *= d; a.y *= d; a.z *= d; a.w *= d;

  float4 f1 = shx4(a, 1), f2 = shx4(a, 2), f3 = shx4(a, 3);

  int col0 = q * 10;
  float v[10];
  #pragma unroll
  for (int jj = 0; jj < 10; ++jj) v[jj] = w2s[HDIM * CODIM + col0 + jj];

  {
    const float* wr;
    wr = w2s + ((q ^ 0) * 4 + 0) * CODIM + col0;
    #pragma unroll
    for (int jj = 0; jj < 10; ++jj) v[jj] = fmaf(a.x, wr[jj], v[jj]);
    wr = w2s + ((q ^ 0) * 4 + 1) * CODIM + col0;
    #pragma unroll
    for (int jj = 0; jj < 10; ++jj) v[jj] = fmaf(a.y, wr[jj], v[jj]);
    wr = w2s + ((q ^ 0) * 4 + 2) * CODIM + col0;
    #pragma unroll
    for (int jj = 0; jj < 10; ++jj) v[jj] = fmaf(a.z, wr[jj], v[jj]);
    wr = w2s + ((q ^ 0) * 4 + 3) * CODIM + col0;
    #pragma unroll
    for (int jj = 0; jj < 10; ++jj) v[jj] = fmaf(a.w, wr[jj], v[jj]);

    wr = w2s + ((q ^ 1) * 4 + 0) * CODIM + col0;
    #pragma unroll
    for (int jj = 0; jj < 10; ++jj) v[jj] = fmaf(f1.x, wr[jj], v[jj]);
    wr = w2s + ((q ^ 1) * 4 + 1) * CODIM + col0;
    #pragma unroll
    for (int jj = 0; jj < 10; ++jj) v[jj] = fmaf(f1.y, wr[jj], v[jj]);
    wr = w2s + ((q ^ 1) * 4 + 2) * CODIM + col0;
    #pragma unroll
    for (int jj = 0; jj < 10; ++jj) v[jj] = fmaf(f1.z, wr[jj], v[jj]);
    wr = w2s + ((q ^ 1) * 4 + 3) * CODIM + col0;
    #pragma unroll
    for (int jj = 0; jj < 10; ++jj) v[jj] = fmaf(f1.w, wr[jj], v[jj]);

    wr = w2s + ((q ^ 2) * 4 + 0) * CODIM + col0;
    #pragma unroll
    for (int jj = 0; jj < 10; ++jj) v[jj] = fmaf(f2.x, wr[jj], v[jj]);
    wr = w2s + ((q ^ 2) * 4 + 1) * CODIM + col0;
    #pragma unroll
    for (int jj = 0; jj < 10; ++jj) v[jj] = fmaf(f2.y, wr[jj], v[jj]);
    wr = w2s + ((q ^ 2) * 4 + 2) * CODIM + col0;
    #pragma unroll
    for (int jj = 0; jj < 10; ++jj) v[jj] = fmaf(f2.z, wr[jj], v[jj]);
    wr = w2s + ((q ^ 2) * 4 + 3) * CODIM + col0;
    #pragma unroll
    for (int jj = 0; jj < 10; ++jj) v[jj] = fmaf(f2.w, wr[jj], v[jj]);

    wr = w2s + ((q ^ 3) * 4 + 0) * CODIM + col0;
    #pragma unroll
    for (int jj = 0; jj < 10; ++jj) v[jj] = fmaf(f3.x, wr[jj], v[jj]);
    wr = w2s + ((q ^ 3) * 4 + 1) * CODIM + col0;
    #pragma unroll
    for (int jj = 0; jj < 10; ++jj) v[jj] = fmaf(f3.y, wr[jj], v[jj]);
    wr = w2s + ((q ^ 3) * 4 + 2) * CODIM + col0;
    #pragma unroll
    for (int jj = 0; jj < 10; ++jj) v[jj] = fmaf(f3.z, wr[jj], v[jj]);
    wr = w2s + ((q ^ 3) * 4 + 3) * CODIM + col0;
    #pragma unroll
    for (int jj = 0; jj < 10; ++jj) v[jj] = fmaf(f3.w, wr[jj], v[jj]);
  }

  float m = v[0];
  #pragma unroll
  for (int jj = 1; jj < 10; ++jj) m = fmaxf(m, v[jj]);
  m = fmaxf(m, __shfl_xor(m, 1));
  m = fmaxf(m, __shfl_xor(m, 2));
  float sum = 0.f;
  #pragma unroll
  for (int jj = 0; jj < 10; ++jj) sum += __expf(v[jj] - m);
  sum += __shfl_xor(sum, 1);
  sum += __shfl_xor(sum, 2);
  float lse = __logf(sum) + m;
  float* o = out + (size_t)node * CODIM + col0;
  #pragma unroll
  for (int jj = 0; jj < 10; ++jj) o[jj] = v[jj] - lse;
}

extern "C" void kernel_launch(void* const* d_in, const int* in_sizes, int n_in,
                              void* d_out, int out_size, void* d_ws, size_t ws_size,
                              hipStream_t stream) {
  const float* x  = (const float*)d_in[0];
  const int*   ei = (const int*)d_in[1];   // [2, E]: row0=src, row1=dst
  const float* ew = (const float*)d_in[2];
  const float* W1 = (const float*)d_in[3];
  const float* b1 = (const float*)d_in[4];
  const float* W2 = (const float*)d_in[5];
  const float* b2 = (const float*)d_in[6];
  float* out = (float*)d_out;

  int N = in_sizes[0] / CIN;
  int E = in_sizes[2];
  const int* src = ei;
  const int* dst = ei + E;
  int NB = (N + BINSZ - 1) >> BSHIFT;

  // ---- workspace layout (y1 aliases dead padded-binned region) ----
  size_t NA = ((size_t)N + 255) & ~(size_t)255;
  size_t NP = ((size_t)N + 2) & ~(size_t)1;
  int*   cursor = (int*)d_ws;                       // NBMAX (counts after binB)
  int*   binoff = cursor + NBMAX;                   // NBMAX+1 -> pad +4
  int*   rowptr = binoff + NBMAX + 4;               // NP
  int2*  csr    = (int2*)(rowptr + NP);             // E
  float* dis    = (float*)(csr + E);                // NA
  unsigned short* zb = (unsigned short*)(dis + NA); // NA*16 bf16 (z table)
  uint2* binned = (uint2*)(zb + NA * 16);           // NB*CAP (dead after k_csrbin)
  unsigned short* y1 = (unsigned short*)binned;     // NA*16 bf16 (aliases binned)

  int gG   = (N + 63) / 64;
  int gG2  = (N + 127) / 128;
  int gEB  = (E + EB - 1) / EB;

  k_zero    <<<(NB + 255) / 256, 256, 0, stream>>>(cursor, NB);
  k_binB    <<<gEB, 256, 0, stream>>>(src, dst, ew, cursor, binned, E);
  k_scanBins<<<1, 256, 0, stream>>>(cursor, binoff, rowptr, NB, N);
  k_csrbin  <<<NB, 1024, 0, stream>>>(binoff, binned, rowptr, csr, dis, N);

  k_gemm1   <<<gG2, 256, 0, stream>>>(x, W1, dis, y1, N);
  k_aggZ    <<<gG, 256, 0, stream>>>(rowptr, csr, y1, zb, dis, b1, N);
  k_aggF    <<<gG, 256, 0, stream>>>(rowptr, csr, zb, out, dis, W2, b2, N);
}

// Round 22
// 248.820 us; speedup vs baseline: 1.0762x; 1.0762x over previous
//
#include <hip/hip_runtime.h>

#define CIN  512
#define HDIM 16
#define CODIM 40
#define BINSZ 256      // nodes per bin
#define BSHIFT 8
#define NBMAX 512      // max bins (N <= 131072)
#define EB 4096        // edges per binning block (16/thread at 256 threads)
#define CAP 9216       // padded per-bin capacity (mean 8184 + 11 sigma)
#define WSTR 36        // gemm1: uints per 4-k group (32 data + 4 pad; 36 % 32 == 4)

__device__ __forceinline__ void fma4(float4& a, float s, float4 b) {
  a.x = fmaf(s, b.x, a.x);
  a.y = fmaf(s, b.y, a.y);
  a.z = fmaf(s, b.z, a.z);
  a.w = fmaf(s, b.w, a.w);
}

__device__ __forceinline__ float4 red4(float4 v) {
  v.x += __shfl_xor(v.x, 1); v.y += __shfl_xor(v.y, 1);
  v.z += __shfl_xor(v.z, 1); v.w += __shfl_xor(v.w, 1);
  v.x += __shfl_xor(v.x, 2); v.y += __shfl_xor(v.y, 2);
  v.z += __shfl_xor(v.z, 2); v.w += __shfl_xor(v.w, 2);
  return v;
}

__device__ __forceinline__ float4 shx4(float4 v, int m) {
  return make_float4(__shfl_xor(v.x, m), __shfl_xor(v.y, m),
                     __shfl_xor(v.z, m), __shfl_xor(v.w, m));
}

// bf16 (stored as ushort/uint) helpers: f32 accumulate, bf16 storage
__device__ __forceinline__ float4 bf4(ushort4 u) {
  return make_float4(__uint_as_float((unsigned)u.x << 16),
                     __uint_as_float((unsigned)u.y << 16),
                     __uint_as_float((unsigned)u.z << 16),
                     __uint_as_float((unsigned)u.w << 16));
}
__device__ __forceinline__ unsigned short f2bf(float f) {
  unsigned u = __float_as_uint(f);
  return (unsigned short)((u + 0x7FFFu + ((u >> 16) & 1u)) >> 16);
}
__device__ __forceinline__ ushort4 pk4(float4 v) {
  ushort4 r;
  r.x = f2bf(v.x); r.y = f2bf(v.y); r.z = f2bf(v.z); r.w = f2bf(v.w);
  return r;
}
__device__ __forceinline__ unsigned pk2(float lo, float hi) {
  return (unsigned)f2bf(lo) | ((unsigned)f2bf(hi) << 16);
}
__device__ __forceinline__ float bl(unsigned u) { return __uint_as_float(u << 16); }
__device__ __forceinline__ float bh(unsigned u) { return __uint_as_float(u & 0xFFFF0000u); }

__global__ void k_zero(int* __restrict__ p, int n) {
  int i = blockIdx.x * 256 + threadIdx.x;
  if (i < n) p[i] = 0;
}

// single-pass binning into fixed-capacity padded bins; int4 vectorized loads.
__global__ __launch_bounds__(256) void k_binB(const int* __restrict__ src,
                                              const int* __restrict__ dst,
                                              const float* __restrict__ w,
                                              int* __restrict__ cursor,
                                              uint2* __restrict__ binned, int E) {
  __shared__ int hist[NBMAX];
  __shared__ int base[NBMAX];
  int t = threadIdx.x;
  for (int i = t; i < NBMAX; i += 256) hist[i] = 0;
  __syncthreads();
  int beg = blockIdx.x * EB, end = min(E, beg + EB);
  int dbuf[16];
  #pragma unroll
  for (int j = 0; j < 4; ++j) {
    int e = beg + t * 4 + j * 1024;
    if (e + 3 < end) {
      int4 d4 = *(const int4*)(dst + e);
      dbuf[4 * j + 0] = d4.x; dbuf[4 * j + 1] = d4.y;
      dbuf[4 * j + 2] = d4.z; dbuf[4 * j + 3] = d4.w;
      atomicAdd(&hist[d4.x >> BSHIFT], 1);
      atomicAdd(&hist[d4.y >> BSHIFT], 1);
      atomicAdd(&hist[d4.z >> BSHIFT], 1);
      atomicAdd(&hist[d4.w >> BSHIFT], 1);
    } else {
      #pragma unroll
      for (int k = 0; k < 4; ++k) {
        int ee = e + k;
        int d = (ee < end) ? dst[ee] : -1;
        dbuf[4 * j + k] = d;
        if (d >= 0) atomicAdd(&hist[d >> BSHIFT], 1);
      }
    }
  }
  __syncthreads();
  for (int i = t; i < NBMAX; i += 256) {
    int h = hist[i];
    base[i] = h ? (i * CAP + atomicAdd(&cursor[i], h)) : 0;
  }
  __syncthreads();
  #pragma unroll
  for (int j = 0; j < 4; ++j) {
    int e = beg + t * 4 + j * 1024;
    if (e + 3 < end) {
      int4   s4 = *(const int4*)(src + e);
      float4 w4 = *(const float4*)(w + e);
      int ss[4] = {s4.x, s4.y, s4.z, s4.w};
      float ww[4] = {w4.x, w4.y, w4.z, w4.w};
      #pragma unroll
      for (int k = 0; k < 4; ++k) {
        int d = dbuf[4 * j + k];
        int b = d >> BSHIFT;
        int pos = atomicAdd(&base[b], 1);
        binned[pos] = make_uint2((unsigned)ss[k] | ((unsigned)(d & (BINSZ - 1)) << 17),
                                 __float_as_uint(ww[k]));
      }
    } else {
      #pragma unroll
      for (int k = 0; k < 4; ++k) {
        int ee = e + k;
        int d = dbuf[4 * j + k];
        if (d >= 0) {
          int b = d >> BSHIFT;
          int pos = atomicAdd(&base[b], 1);
          binned[pos] = make_uint2((unsigned)src[ee] | ((unsigned)(d & (BINSZ - 1)) << 17),
                                   __float_as_uint(w[ee]));
        }
      }
    }
  }
}

// scan bin counts -> compact csr offsets (cursor holds counts after binB)
__global__ __launch_bounds__(256) void k_scanBins(
    const int* __restrict__ cnt, int* __restrict__ binoff,
    int* __restrict__ rowptr, int NB, int N) {
  __shared__ int ts[256];
  int t = threadIdx.x;
  int c0 = (2 * t     < NB) ? cnt[2 * t]     : 0;
  int c1 = (2 * t + 1 < NB) ? cnt[2 * t + 1] : 0;
  int s = c0 + c1;
  ts[t] = s;
  __syncthreads();
  #pragma unroll
  for (int off = 1; off < 256; off <<= 1) {
    int v = (t >= off) ? ts[t - off] : 0;
    __syncthreads();
    ts[t] += v;
    __syncthreads();
  }
  int ex = ts[t] - s;
  if (2 * t     < NB) binoff[2 * t]     = ex;
  if (2 * t + 1 < NB) binoff[2 * t + 1] = ex + c0;
  if (t == 255) { binoff[NB] = ts[255]; rowptr[N] = ts[255]; }
}

// per-bin counting sort: padded binned -> compact node-sorted csr + rowptr + dis.
// uint4 paired loads; wave-shfl scan over the 256-entry hist.
__global__ __launch_bounds__(1024) void k_csrbin(
    const int* __restrict__ binoff, const uint2* __restrict__ binned,
    int* __restrict__ rowptr, int2* __restrict__ csr,
    float* __restrict__ dis, int N) {
  __shared__ int   hist[BINSZ];
  __shared__ int   loff[BINSZ];
  __shared__ int   rank[BINSZ];
  __shared__ float dsum[BINSZ];
  __shared__ int   wsum[4];
  int t = threadIdx.x, b = blockIdx.x;
  if (t < BINSZ) { hist[t] = 0; rank[t] = 0; dsum[t] = 1.0f; }  // self-loop deg = 1
  __syncthreads();
  int cbeg = binoff[b], cnt = binoff[b + 1] - cbeg;
  size_t pbeg = (size_t)b * CAP;
  uint4 eb2[5];   // 5 pairs = 10 edges/thread; 10240 >= CAP
  #pragma unroll
  for (int j = 0; j < 5; ++j) {
    int p = t + j * 1024;
    int i0 = p * 2;
    if (i0 + 1 < cnt) {
      uint4 E2 = *(const uint4*)(binned + pbeg + i0);
      eb2[j] = E2;
      int dl0 = E2.x >> 17, dl1 = E2.z >> 17;
      atomicAdd(&hist[dl0], 1);
      atomicAdd(&dsum[dl0], __uint_as_float(E2.y));
      atomicAdd(&hist[dl1], 1);
      atomicAdd(&dsum[dl1], __uint_as_float(E2.w));
    } else if (i0 < cnt) {
      uint2 e = binned[pbeg + i0];
      eb2[j].x = e.x; eb2[j].y = e.y;
      int dl = e.x >> 17;
      atomicAdd(&hist[dl], 1);
      atomicAdd(&dsum[dl], __uint_as_float(e.y));
    }
  }
  __syncthreads();
  // wave-level inclusive scan over 256 entries (waves 0-3), combine via wsum
  int h = 0, inc = 0;
  if (t < BINSZ) {
    h = hist[t];
    inc = h;
    #pragma unroll
    for (int off = 1; off < 64; off <<= 1) {
      int v = __shfl_up(inc, off);
      if ((t & 63) >= off) inc += v;
    }
    if ((t & 63) == 63) wsum[t >> 6] = inc;
  }
  __syncthreads();
  if (t < BINSZ) {
    int wid = t >> 6;
    int wadd = 0;
    #pragma unroll
    for (int wv = 0; wv < 3; ++wv) if (wv < wid) wadd += wsum[wv];
    int ex = inc - h + wadd;
    int n = b * BINSZ + t;
    if (n < N) {
      rowptr[n] = cbeg + ex;
      dis[n] = rsqrtf(dsum[t]);
    }
    loff[t] = ex;
  }
  __syncthreads();
  #pragma unroll
  for (int j = 0; j < 5; ++j) {
    int p = t + j * 1024;
    int i0 = p * 2;
    if (i0 < cnt) {
      unsigned ex = eb2[j].x, ey = eb2[j].y;
      int dl = ex >> 17;
      int r = atomicAdd(&rank[dl], 1);
      csr[cbeg + loff[dl] + r] = make_int2((int)(ex & 0x1FFFFu), (int)ey);
    }
    if (i0 + 1 < cnt) {
      unsigned ez = eb2[j].z, ew = eb2[j].w;
      int dl = ez >> 17;
      int r = atomicAdd(&rank[dl], 1);
      csr[cbeg + loff[dl] + r] = make_int2((int)(ez & 0x1FFFFu), (int)ew);
    }
  }
}

// 16 bf16-pair FMAs: cols 0..15 of one W1 row, scale s
__device__ __forceinline__ void dot16(float4& a0, float4& a1, float4& a2, float4& a3,
                                      uint4 U0, uint4 U1, float s) {
  a0.x = fmaf(s, bl(U0.x), a0.x); a0.y = fmaf(s, bh(U0.x), a0.y);
  a0.z = fmaf(s, bl(U0.y), a0.z); a0.w = fmaf(s, bh(U0.y), a0.w);
  a1.x = fmaf(s, bl(U0.z), a1.x); a1.y = fmaf(s, bh(U0.z), a1.y);
  a1.z = fmaf(s, bl(U0.w), a1.z); a1.w = fmaf(s, bh(U0.w), a1.w);
  a2.x = fmaf(s, bl(U1.x), a2.x); a2.y = fmaf(s, bh(U1.x), a2.y);
  a2.z = fmaf(s, bl(U1.y), a2.z); a2.w = fmaf(s, bh(U1.y), a2.w);
  a3.x = fmaf(s, bl(U1.z), a3.x); a3.y = fmaf(s, bh(U1.z), a3.y);
  a3.z = fmaf(s, bl(U1.w), a3.z); a3.w = fmaf(s, bh(U1.w), a3.w);
}

// y1[n][:] = bf16( dis[n] * (x[n][:] @ W1) )
// v5: 4 lanes/node, 1 node/lane, W1 staged in LDS as bf16 pairs (18.4 KB).
__global__ __launch_bounds__(256, 4) void k_gemm1(
    const float* __restrict__ x, const float* __restrict__ W1,
    const float* __restrict__ dis, unsigned short* __restrict__ y1, int N) {
  __shared__ unsigned w1s[128 * WSTR];  // 18.4 KB
  int t = threadIdx.x;
  const float4* W14 = (const float4*)W1;  // 2048 float4
  for (int lin = t; lin < 2048; lin += 256) {
    float4 v = W14[lin];
    int g = lin >> 4, f = lin & 15;                 // group, float4-within-group
    unsigned* p = w1s + g * WSTR + (f >> 2) * 8 + (f & 3) * 2;
    p[0] = pk2(v.x, v.y);
    p[1] = pk2(v.z, v.w);
  }
  __syncthreads();

  int quad = t >> 2;
  int q = t & 3;
  int n = blockIdx.x * 64 + quad;
  if (n >= N) return;

  const float4* xr = (const float4*)x + (size_t)n * (CIN / 4);
  float4 a0 = make_float4(0.f, 0.f, 0.f, 0.f), a1 = a0, a2 = a0, a3 = a0;

  #pragma unroll 4
  for (int kk = 0; kk < 32; ++kk) {
    float4 xa = xr[kk * 4 + q];
    const uint4* wr = (const uint4*)(w1s + (kk * 4 + q) * WSTR);
    dot16(a0, a1, a2, a3, wr[0], wr[1], xa.x);
    dot16(a0, a1, a2, a3, wr[2], wr[3], xa.y);
    dot16(a0, a1, a2, a3, wr[4], wr[5], xa.z);
    dot16(a0, a1, a2, a3, wr[6], wr[7], xa.w);
  }
  a0 = red4(a0); a1 = red4(a1); a2 = red4(a2); a3 = red4(a3);

  float d = dis[n];
  float4 sel = (q == 0) ? a0 : (q == 1) ? a1 : (q == 2) ? a2 : a3;
  sel.x *= d; sel.y *= d; sel.z *= d; sel.w *= d;
  ((ushort4*)y1)[(size_t)n * 4 + q] = pk4(sel);
}

// 8-deep unrolled row gather-accumulate over bf16 table
__device__ __forceinline__ float4 rowAccB(const int2* __restrict__ csr,
                                          const ushort4* __restrict__ v4,
                                          float4 s0, int beg, int end, int q) {
  float4 s1 = make_float4(0.f, 0.f, 0.f, 0.f), s2 = s1, s3 = s1;
  int i = beg;
  for (; i + 7 < end; i += 8) {
    int2 e0 = csr[i],     e1 = csr[i + 1], e2 = csr[i + 2], e3 = csr[i + 3];
    int2 e4 = csr[i + 4], e5 = csr[i + 5], e6 = csr[i + 6], e7 = csr[i + 7];
    ushort4 u0 = v4[(size_t)e0.x * 4 + q];
    ushort4 u1 = v4[(size_t)e1.x * 4 + q];
    ushort4 u2 = v4[(size_t)e2.x * 4 + q];
    ushort4 u3 = v4[(size_t)e3.x * 4 + q];
    ushort4 u4 = v4[(size_t)e4.x * 4 + q];
    ushort4 u5 = v4[(size_t)e5.x * 4 + q];
    ushort4 u6 = v4[(size_t)e6.x * 4 + q];
    ushort4 u7 = v4[(size_t)e7.x * 4 + q];
    fma4(s0, __int_as_float(e0.y), bf4(u0));
    fma4(s1, __int_as_float(e1.y), bf4(u1));
    fma4(s2, __int_as_float(e2.y), bf4(u2));
    fma4(s3, __int_as_float(e3.y), bf4(u3));
    fma4(s0, __int_as_float(e4.y), bf4(u4));
    fma4(s1, __int_as_float(e5.y), bf4(u5));
    fma4(s2, __int_as_float(e6.y), bf4(u6));
    fma4(s3, __int_as_float(e7.y), bf4(u7));
  }
  for (; i < end; ++i) {
    int2 e = csr[i];
    fma4(s0, __int_as_float(e.y), bf4(v4[(size_t)e.x * 4 + q]));
  }
  s0.x += s1.x + s2.x + s3.x;
  s0.y += s1.y + s2.y + s3.y;
  s0.z += s1.z + s2.z + s3.z;
  s0.w += s1.w + s2.w + s3.w;
  return s0;
}

// aggregate + z epilogue (bf16 in, bf16 out)
__global__ __launch_bounds__(256) void k_aggZ(
    const int* __restrict__ rowptr, const int2* __restrict__ csr,
    const unsigned short* __restrict__ vals, unsigned short* __restrict__ zb,
    const float* __restrict__ dis, const float* __restrict__ b1, int N) {
  int t = threadIdx.x;
  int node = blockIdx.x * 64 + (t >> 2);
  int q = t & 3;
  if (node >= N) return;
  const ushort4* v4 = (const ushort4*)vals;
  float4 a = rowAccB(csr, v4, bf4(v4[(size_t)node * 4 + q]),
                     rowptr[node], rowptr[node + 1], q);
  float d = dis[node];
  float4 bb = ((const float4*)b1)[q];
  float4 z;
  z.x = d * fmaxf(fmaf(d, a.x, bb.x), 0.f);
  z.y = d * fmaxf(fmaf(d, a.y, bb.y), 0.f);
  z.z = d * fmaxf(fmaf(d, a.z, bb.z), 0.f);
  z.w = d * fmaxf(fmaf(d, a.w, bb.w), 0.f);
  ((ushort4*)zb)[(size_t)node * 4 + q] = pk4(z);
}

// aggregate + final epilogue (bf16 in, W2 matmul + log_softmax, f32 out)
__global__ __launch_bounds__(256) void k_aggF(
    const int* __restrict__ rowptr, const int2* __restrict__ csr,
    const unsigned short* __restrict__ vals, float* __restrict__ out,
    const float* __restrict__ dis, const float* __restrict__ W2,
    const float* __restrict__ b2, int N) {
  __shared__ float w2s[HDIM * CODIM + CODIM];
  int t = threadIdx.x;
  for (int i = t; i < HDIM * CODIM; i += 256) w2s[i] = W2[i];
  if (t < CODIM) w2s[HDIM * CODIM + t] = b2[t];
  __syncthreads();

  int node = blockIdx.x * 64 + (t >> 2);
  int q = t & 3;
  if (node >= N) return;
  const ushort4* v4 = (const ushort4*)vals;
  float4 a = rowAccB(csr, v4, bf4(v4[(size_t)node * 4 + q]),
                     rowptr[node], rowptr[node + 1], q);
  float d = dis[node];
  a.x *= d; a.y *= d; a.z *= d; a.w *= d;

  float4 f1 = shx4(a, 1), f2 = shx4(a, 2), f3 = shx4(a, 3);

  int col0 = q * 10;
  float v[10];
  #pragma unroll
  for (int jj = 0; jj < 10; ++jj) v[jj] = w2s[HDIM * CODIM + col0 + jj];

  {
    const float* wr;
    wr = w2s + ((q ^ 0) * 4 + 0) * CODIM + col0;
    #pragma unroll
    for (int jj = 0; jj < 10; ++jj) v[jj] = fmaf(a.x, wr[jj], v[jj]);
    wr = w2s + ((q ^ 0) * 4 + 1) * CODIM + col0;
    #pragma unroll
    for (int jj = 0; jj < 10; ++jj) v[jj] = fmaf(a.y, wr[jj], v[jj]);
    wr = w2s + ((q ^ 0) * 4 + 2) * CODIM + col0;
    #pragma unroll
    for (int jj = 0; jj < 10; ++jj) v[jj] = fmaf(a.z, wr[jj], v[jj]);
    wr = w2s + ((q ^ 0) * 4 + 3) * CODIM + col0;
    #pragma unroll
    for (int jj = 0; jj < 10; ++jj) v[jj] = fmaf(a.w, wr[jj], v[jj]);

    wr = w2s + ((q ^ 1) * 4 + 0) * CODIM + col0;
    #pragma unroll
    for (int jj = 0; jj < 10; ++jj) v[jj] = fmaf(f1.x, wr[jj], v[jj]);
    wr = w2s + ((q ^ 1) * 4 + 1) * CODIM + col0;
    #pragma unroll
    for (int jj = 0; jj < 10; ++jj) v[jj] = fmaf(f1.y, wr[jj], v[jj]);
    wr = w2s + ((q ^ 1) * 4 + 2) * CODIM + col0;
    #pragma unroll
    for (int jj = 0; jj < 10; ++jj) v[jj] = fmaf(f1.z, wr[jj], v[jj]);
    wr = w2s + ((q ^ 1) * 4 + 3) * CODIM + col0;
    #pragma unroll
    for (int jj = 0; jj < 10; ++jj) v[jj] = fmaf(f1.w, wr[jj], v[jj]);

    wr = w2s + ((q ^ 2) * 4 + 0) * CODIM + col0;
    #pragma unroll
    for (int jj = 0; jj < 10; ++jj) v[jj] = fmaf(f2.x, wr[jj], v[jj]);
    wr = w2s + ((q ^ 2) * 4 + 1) * CODIM + col0;
    #pragma unroll
    for (int jj = 0; jj < 10; ++jj) v[jj] = fmaf(f2.y, wr[jj], v[jj]);
    wr = w2s + ((q ^ 2) * 4 + 2) * CODIM + col0;
    #pragma unroll
    for (int jj = 0; jj < 10; ++jj) v[jj] = fmaf(f2.z, wr[jj], v[jj]);
    wr = w2s + ((q ^ 2) * 4 + 3) * CODIM + col0;
    #pragma unroll
    for (int jj = 0; jj < 10; ++jj) v[jj] = fmaf(f2.w, wr[jj], v[jj]);

    wr = w2s + ((q ^ 3) * 4 + 0) * CODIM + col0;
    #pragma unroll
    for (int jj = 0; jj < 10; ++jj) v[jj] = fmaf(f3.x, wr[jj], v[jj]);
    wr = w2s + ((q ^ 3) * 4 + 1) * CODIM + col0;
    #pragma unroll
    for (int jj = 0; jj < 10; ++jj) v[jj] = fmaf(f3.y, wr[jj], v[jj]);
    wr = w2s + ((q ^ 3) * 4 + 2) * CODIM + col0;
    #pragma unroll
    for (int jj = 0; jj < 10; ++jj) v[jj] = fmaf(f3.z, wr[jj], v[jj]);
    wr = w2s + ((q ^ 3) * 4 + 3) * CODIM + col0;
    #pragma unroll
    for (int jj = 0; jj < 10; ++jj) v[jj] = fmaf(f3.w, wr[jj], v[jj]);
  }

  float m = v[0];
  #pragma unroll
  for (int jj = 1; jj < 10; ++jj) m = fmaxf(m, v[jj]);
  m = fmaxf(m, __shfl_xor(m, 1));
  m = fmaxf(m, __shfl_xor(m, 2));
  float sum = 0.f;
  #pragma unroll
  for (int jj = 0; jj < 10; ++jj) sum += __expf(v[jj] - m);
  sum += __shfl_xor(sum, 1);
  sum += __shfl_xor(sum, 2);
  float lse = __logf(sum) + m;
  float* o = out + (size_t)node * CODIM + col0;
  #pragma unroll
  for (int jj = 0; jj < 10; ++jj) o[jj] = v[jj] - lse;
}

extern "C" void kernel_launch(void* const* d_in, const int* in_sizes, int n_in,
                              void* d_out, int out_size, void* d_ws, size_t ws_size,
                              hipStream_t stream) {
  const float* x  = (const float*)d_in[0];
  const int*   ei = (const int*)d_in[1];   // [2, E]: row0=src, row1=dst
  const float* ew = (const float*)d_in[2];
  const float* W1 = (const float*)d_in[3];
  const float* b1 = (const float*)d_in[4];
  const float* W2 = (const float*)d_in[5];
  const float* b2 = (const float*)d_in[6];
  float* out = (float*)d_out;

  int N = in_sizes[0] / CIN;
  int E = in_sizes[2];
  const int* src = ei;
  const int* dst = ei + E;
  int NB = (N + BINSZ - 1) >> BSHIFT;

  // ---- workspace layout (y1 aliases dead padded-binned region) ----
  size_t NA = ((size_t)N + 255) & ~(size_t)255;
  size_t NP = ((size_t)N + 2) & ~(size_t)1;
  int*   cursor = (int*)d_ws;                       // NBMAX (counts after binB)
  int*   binoff = cursor + NBMAX;                   // NBMAX+1 -> pad +4
  int*   rowptr = binoff + NBMAX + 4;               // NP
  int2*  csr    = (int2*)(rowptr + NP);             // E
  float* dis    = (float*)(csr + E);                // NA
  unsigned short* zb = (unsigned short*)(dis + NA); // NA*16 bf16 (z table)
  uint2* binned = (uint2*)(zb + NA * 16);           // NB*CAP (dead after k_csrbin)
  unsigned short* y1 = (unsigned short*)binned;     // NA*16 bf16 (aliases binned)

  int gG   = (N + 63) / 64;
  int gEB  = (E + EB - 1) / EB;

  k_zero    <<<(NB + 255) / 256, 256, 0, stream>>>(cursor, NB);
  k_binB    <<<gEB, 256, 0, stream>>>(src, dst, ew, cursor, binned, E);
  k_scanBins<<<1, 256, 0, stream>>>(cursor, binoff, rowptr, NB, N);
  k_csrbin  <<<NB, 1024, 0, stream>>>(binoff, binned, rowptr, csr, dis, N);

  k_gemm1   <<<gG, 256, 0, stream>>>(x, W1, dis, y1, N);
  k_aggZ    <<<gG, 256, 0, stream>>>(rowptr, csr, y1, zb, dis, b1, N);
  k_aggF    <<<gG, 256, 0, stream>>>(rowptr, csr, zb, out, dis, W2, b2, N);
}

// Round 23
// 245.604 us; speedup vs baseline: 1.0902x; 1.0131x over previous
//
#include <hip/hip_runtime.h>

#define CIN  512
#define HDIM 16
#define CODIM 40
#define BINSZ 256      // nodes per bin
#define BSHIFT 8
#define NBMAX 512      // max bins (N <= 131072)
#define EB 4096        // edges per binning block (16/thread at 256 threads)
#define CAP 9216       // padded per-bin capacity (mean 8184 + 11 sigma)
#define WSTR 36        // gemm1: uints per 4-k group (32 data + 4 pad; 36 % 32 == 4)

__device__ __forceinline__ void fma4(float4& a, float s, float4 b) {
  a.x = fmaf(s, b.x, a.x);
  a.y = fmaf(s, b.y, a.y);
  a.z = fmaf(s, b.z, a.z);
  a.w = fmaf(s, b.w, a.w);
}

__device__ __forceinline__ float4 red4(float4 v) {
  v.x += __shfl_xor(v.x, 1); v.y += __shfl_xor(v.y, 1);
  v.z += __shfl_xor(v.z, 1); v.w += __shfl_xor(v.w, 1);
  v.x += __shfl_xor(v.x, 2); v.y += __shfl_xor(v.y, 2);
  v.z += __shfl_xor(v.z, 2); v.w += __shfl_xor(v.w, 2);
  return v;
}

__device__ __forceinline__ float4 shx4(float4 v, int m) {
  return make_float4(__shfl_xor(v.x, m), __shfl_xor(v.y, m),
                     __shfl_xor(v.z, m), __shfl_xor(v.w, m));
}

// bf16 (stored as ushort/uint) helpers: f32 accumulate, bf16 storage
__device__ __forceinline__ float4 bf4(ushort4 u) {
  return make_float4(__uint_as_float((unsigned)u.x << 16),
                     __uint_as_float((unsigned)u.y << 16),
                     __uint_as_float((unsigned)u.z << 16),
                     __uint_as_float((unsigned)u.w << 16));
}
__device__ __forceinline__ unsigned short f2bf(float f) {
  unsigned u = __float_as_uint(f);
  return (unsigned short)((u + 0x7FFFu + ((u >> 16) & 1u)) >> 16);
}
__device__ __forceinline__ ushort4 pk4(float4 v) {
  ushort4 r;
  r.x = f2bf(v.x); r.y = f2bf(v.y); r.z = f2bf(v.z); r.w = f2bf(v.w);
  return r;
}
__device__ __forceinline__ unsigned pk2(float lo, float hi) {
  return (unsigned)f2bf(lo) | ((unsigned)f2bf(hi) << 16);
}
__device__ __forceinline__ float bl(unsigned u) { return __uint_as_float(u << 16); }
__device__ __forceinline__ float bh(unsigned u) { return __uint_as_float(u & 0xFFFF0000u); }

__global__ void k_zero(int* __restrict__ p, int n) {
  int i = blockIdx.x * 256 + threadIdx.x;
  if (i < n) p[i] = 0;
}

// single-pass binning into fixed-capacity padded bins; int4 vectorized loads.
// Local rank captured from the FIRST hist atomic's return value -> write phase
// needs only a plain LDS read (one LDS atomic per edge, not two).
__global__ __launch_bounds__(256) void k_binB(const int* __restrict__ src,
                                              const int* __restrict__ dst,
                                              const float* __restrict__ w,
                                              int* __restrict__ cursor,
                                              uint2* __restrict__ binned, int E) {
  __shared__ int hist[NBMAX];
  __shared__ int base[NBMAX];
  int t = threadIdx.x;
  for (int i = t; i < NBMAX; i += 256) hist[i] = 0;
  __syncthreads();
  int beg = blockIdx.x * EB, end = min(E, beg + EB);
  int dbuf[16];
  int rbuf[16];
  #pragma unroll
  for (int j = 0; j < 4; ++j) {
    int e = beg + t * 4 + j * 1024;
    if (e + 3 < end) {
      int4 d4 = *(const int4*)(dst + e);
      dbuf[4 * j + 0] = d4.x; dbuf[4 * j + 1] = d4.y;
      dbuf[4 * j + 2] = d4.z; dbuf[4 * j + 3] = d4.w;
      rbuf[4 * j + 0] = atomicAdd(&hist[d4.x >> BSHIFT], 1);
      rbuf[4 * j + 1] = atomicAdd(&hist[d4.y >> BSHIFT], 1);
      rbuf[4 * j + 2] = atomicAdd(&hist[d4.z >> BSHIFT], 1);
      rbuf[4 * j + 3] = atomicAdd(&hist[d4.w >> BSHIFT], 1);
    } else {
      #pragma unroll
      for (int k = 0; k < 4; ++k) {
        int ee = e + k;
        int d = (ee < end) ? dst[ee] : -1;
        dbuf[4 * j + k] = d;
        rbuf[4 * j + k] = (d >= 0) ? atomicAdd(&hist[d >> BSHIFT], 1) : 0;
      }
    }
  }
  __syncthreads();
  for (int i = t; i < NBMAX; i += 256) {
    int h = hist[i];
    base[i] = h ? (i * CAP + atomicAdd(&cursor[i], h)) : 0;
  }
  __syncthreads();
  #pragma unroll
  for (int j = 0; j < 4; ++j) {
    int e = beg + t * 4 + j * 1024;
    if (e + 3 < end) {
      int4   s4 = *(const int4*)(src + e);
      float4 w4 = *(const float4*)(w + e);
      int ss[4] = {s4.x, s4.y, s4.z, s4.w};
      float ww[4] = {w4.x, w4.y, w4.z, w4.w};
      #pragma unroll
      for (int k = 0; k < 4; ++k) {
        int d = dbuf[4 * j + k];
        int b = d >> BSHIFT;
        int pos = base[b] + rbuf[4 * j + k];
        binned[pos] = make_uint2((unsigned)ss[k] | ((unsigned)(d & (BINSZ - 1)) << 17),
                                 __float_as_uint(ww[k]));
      }
    } else {
      #pragma unroll
      for (int k = 0; k < 4; ++k) {
        int ee = e + k;
        int d = dbuf[4 * j + k];
        if (d >= 0) {
          int b = d >> BSHIFT;
          int pos = base[b] + rbuf[4 * j + k];
          binned[pos] = make_uint2((unsigned)src[ee] | ((unsigned)(d & (BINSZ - 1)) << 17),
                                   __float_as_uint(w[ee]));
        }
      }
    }
  }
}

// scan bin counts -> compact csr offsets (cursor holds counts after binB)
__global__ __launch_bounds__(256) void k_scanBins(
    const int* __restrict__ cnt, int* __restrict__ binoff,
    int* __restrict__ rowptr, int NB, int N) {
  __shared__ int ts[256];
  int t = threadIdx.x;
  int c0 = (2 * t     < NB) ? cnt[2 * t]     : 0;
  int c1 = (2 * t + 1 < NB) ? cnt[2 * t + 1] : 0;
  int s = c0 + c1;
  ts[t] = s;
  __syncthreads();
  #pragma unroll
  for (int off = 1; off < 256; off <<= 1) {
    int v = (t >= off) ? ts[t - off] : 0;
    __syncthreads();
    ts[t] += v;
    __syncthreads();
  }
  int ex = ts[t] - s;
  if (2 * t     < NB) binoff[2 * t]     = ex;
  if (2 * t + 1 < NB) binoff[2 * t + 1] = ex + c0;
  if (t == 255) { binoff[NB] = ts[255]; rowptr[N] = ts[255]; }
}

// per-bin counting sort: padded binned -> compact node-sorted csr + rowptr + dis.
// uint4 paired loads; wave-shfl scan; rank captured from first hist atomic.
__global__ __launch_bounds__(1024) void k_csrbin(
    const int* __restrict__ binoff, const uint2* __restrict__ binned,
    int* __restrict__ rowptr, int2* __restrict__ csr,
    float* __restrict__ dis, int N) {
  __shared__ int   hist[BINSZ];
  __shared__ int   loff[BINSZ];
  __shared__ float dsum[BINSZ];
  __shared__ int   wsum[4];
  int t = threadIdx.x, b = blockIdx.x;
  if (t < BINSZ) { hist[t] = 0; dsum[t] = 1.0f; }  // self-loop deg = 1
  __syncthreads();
  int cbeg = binoff[b], cnt = binoff[b + 1] - cbeg;
  size_t pbeg = (size_t)b * CAP;
  uint4 eb2[5];   // 5 pairs = 10 edges/thread; 10240 >= CAP
  int   rb[10];
  #pragma unroll
  for (int j = 0; j < 5; ++j) {
    int p = t + j * 1024;
    int i0 = p * 2;
    if (i0 + 1 < cnt) {
      uint4 E2 = *(const uint4*)(binned + pbeg + i0);
      eb2[j] = E2;
      int dl0 = E2.x >> 17, dl1 = E2.z >> 17;
      rb[2 * j]     = atomicAdd(&hist[dl0], 1);
      atomicAdd(&dsum[dl0], __uint_as_float(E2.y));
      rb[2 * j + 1] = atomicAdd(&hist[dl1], 1);
      atomicAdd(&dsum[dl1], __uint_as_float(E2.w));
    } else if (i0 < cnt) {
      uint2 e = binned[pbeg + i0];
      eb2[j].x = e.x; eb2[j].y = e.y;
      int dl = e.x >> 17;
      rb[2 * j] = atomicAdd(&hist[dl], 1);
      atomicAdd(&dsum[dl], __uint_as_float(e.y));
    }
  }
  __syncthreads();
  // wave-level inclusive scan over 256 entries (waves 0-3), combine via wsum
  int h = 0, inc = 0;
  if (t < BINSZ) {
    h = hist[t];
    inc = h;
    #pragma unroll
    for (int off = 1; off < 64; off <<= 1) {
      int v = __shfl_up(inc, off);
      if ((t & 63) >= off) inc += v;
    }
    if ((t & 63) == 63) wsum[t >> 6] = inc;
  }
  __syncthreads();
  if (t < BINSZ) {
    int wid = t >> 6;
    int wadd = 0;
    #pragma unroll
    for (int wv = 0; wv < 3; ++wv) if (wv < wid) wadd += wsum[wv];
    int ex = inc - h + wadd;
    int n = b * BINSZ + t;
    if (n < N) {
      rowptr[n] = cbeg + ex;
      dis[n] = rsqrtf(dsum[t]);
    }
    loff[t] = ex;
  }
  __syncthreads();
  #pragma unroll
  for (int j = 0; j < 5; ++j) {
    int p = t + j * 1024;
    int i0 = p * 2;
    if (i0 < cnt) {
      unsigned ex = eb2[j].x, ey = eb2[j].y;
      int dl = ex >> 17;
      csr[cbeg + loff[dl] + rb[2 * j]] = make_int2((int)(ex & 0x1FFFFu), (int)ey);
    }
    if (i0 + 1 < cnt) {
      unsigned ez = eb2[j].z, ew = eb2[j].w;
      int dl = ez >> 17;
      csr[cbeg + loff[dl] + rb[2 * j + 1]] = make_int2((int)(ez & 0x1FFFFu), (int)ew);
    }
  }
}

// 16 bf16-pair FMAs: cols 0..15 of one W1 row, scale s
__device__ __forceinline__ void dot16(float4& a0, float4& a1, float4& a2, float4& a3,
                                      uint4 U0, uint4 U1, float s) {
  a0.x = fmaf(s, bl(U0.x), a0.x); a0.y = fmaf(s, bh(U0.x), a0.y);
  a0.z = fmaf(s, bl(U0.y), a0.z); a0.w = fmaf(s, bh(U0.y), a0.w);
  a1.x = fmaf(s, bl(U0.z), a1.x); a1.y = fmaf(s, bh(U0.z), a1.y);
  a1.z = fmaf(s, bl(U0.w), a1.z); a1.w = fmaf(s, bh(U0.w), a1.w);
  a2.x = fmaf(s, bl(U1.x), a2.x); a2.y = fmaf(s, bh(U1.x), a2.y);
  a2.z = fmaf(s, bl(U1.y), a2.z); a2.w = fmaf(s, bh(U1.y), a2.w);
  a3.x = fmaf(s, bl(U1.z), a3.x); a3.y = fmaf(s, bh(U1.z), a3.y);
  a3.z = fmaf(s, bl(U1.w), a3.z); a3.w = fmaf(s, bh(U1.w), a3.w);
}

// y1[n][:] = bf16( dis[n] * (x[n][:] @ W1) )
// v5: 4 lanes/node, 1 node/lane, W1 staged in LDS as bf16 pairs (18.4 KB).
__global__ __launch_bounds__(256, 4) void k_gemm1(
    const float* __restrict__ x, const float* __restrict__ W1,
    const float* __restrict__ dis, unsigned short* __restrict__ y1, int N) {
  __shared__ unsigned w1s[128 * WSTR];  // 18.4 KB
  int t = threadIdx.x;
  const float4* W14 = (const float4*)W1;  // 2048 float4
  for (int lin = t; lin < 2048; lin += 256) {
    float4 v = W14[lin];
    int g = lin >> 4, f = lin & 15;                 // group, float4-within-group
    unsigned* p = w1s + g * WSTR + (f >> 2) * 8 + (f & 3) * 2;
    p[0] = pk2(v.x, v.y);
    p[1] = pk2(v.z, v.w);
  }
  __syncthreads();

  int quad = t >> 2;
  int q = t & 3;
  int n = blockIdx.x * 64 + quad;
  if (n >= N) return;

  const float4* xr = (const float4*)x + (size_t)n * (CIN / 4);
  float4 a0 = make_float4(0.f, 0.f, 0.f, 0.f), a1 = a0, a2 = a0, a3 = a0;

  #pragma unroll 4
  for (int kk = 0; kk < 32; ++kk) {
    float4 xa = xr[kk * 4 + q];
    const uint4* wr = (const uint4*)(w1s + (kk * 4 + q) * WSTR);
    dot16(a0, a1, a2, a3, wr[0], wr[1], xa.x);
    dot16(a0, a1, a2, a3, wr[2], wr[3], xa.y);
    dot16(a0, a1, a2, a3, wr[4], wr[5], xa.z);
    dot16(a0, a1, a2, a3, wr[6], wr[7], xa.w);
  }
  a0 = red4(a0); a1 = red4(a1); a2 = red4(a2); a3 = red4(a3);

  float d = dis[n];
  float4 sel = (q == 0) ? a0 : (q == 1) ? a1 : (q == 2) ? a2 : a3;
  sel.x *= d; sel.y *= d; sel.z *= d; sel.w *= d;
  ((ushort4*)y1)[(size_t)n * 4 + q] = pk4(sel);
}

// 8-deep unrolled row gather-accumulate over bf16 table
__device__ __forceinline__ float4 rowAccB(const int2* __restrict__ csr,
                                          const ushort4* __restrict__ v4,
                                          float4 s0, int beg, int end, int q) {
  float4 s1 = make_float4(0.f, 0.f, 0.f, 0.f), s2 = s1, s3 = s1;
  int i = beg;
  for (; i + 7 < end; i += 8) {
    int2 e0 = csr[i],     e1 = csr[i + 1], e2 = csr[i + 2], e3 = csr[i + 3];
    int2 e4 = csr[i + 4], e5 = csr[i + 5], e6 = csr[i + 6], e7 = csr[i + 7];
    ushort4 u0 = v4[(size_t)e0.x * 4 + q];
    ushort4 u1 = v4[(size_t)e1.x * 4 + q];
    ushort4 u2 = v4[(size_t)e2.x * 4 + q];
    ushort4 u3 = v4[(size_t)e3.x * 4 + q];
    ushort4 u4 = v4[(size_t)e4.x * 4 + q];
    ushort4 u5 = v4[(size_t)e5.x * 4 + q];
    ushort4 u6 = v4[(size_t)e6.x * 4 + q];
    ushort4 u7 = v4[(size_t)e7.x * 4 + q];
    fma4(s0, __int_as_float(e0.y), bf4(u0));
    fma4(s1, __int_as_float(e1.y), bf4(u1));
    fma4(s2, __int_as_float(e2.y), bf4(u2));
    fma4(s3, __int_as_float(e3.y), bf4(u3));
    fma4(s0, __int_as_float(e4.y), bf4(u4));
    fma4(s1, __int_as_float(e5.y), bf4(u5));
    fma4(s2, __int_as_float(e6.y), bf4(u6));
    fma4(s3, __int_as_float(e7.y), bf4(u7));
  }
  for (; i < end; ++i) {
    int2 e = csr[i];
    fma4(s0, __int_as_float(e.y), bf4(v4[(size_t)e.x * 4 + q]));
  }
  s0.x += s1.x + s2.x + s3.x;
  s0.y += s1.y + s2.y + s3.y;
  s0.z += s1.z + s2.z + s3.z;
  s0.w += s1.w + s2.w + s3.w;
  return s0;
}

// aggregate + z epilogue (bf16 in, bf16 out)
__global__ __launch_bounds__(256) void k_aggZ(
    const int* __restrict__ rowptr, const int2* __restrict__ csr,
    const unsigned short* __restrict__ vals, unsigned short* __restrict__ zb,
    const float* __restrict__ dis, const float* __restrict__ b1, int N) {
  int t = threadIdx.x;
  int node = blockIdx.x * 64 + (t >> 2);
  int q = t & 3;
  if (node >= N) return;
  const ushort4* v4 = (const ushort4*)vals;
  float4 a = rowAccB(csr, v4, bf4(v4[(size_t)node * 4 + q]),
                     rowptr[node], rowptr[node + 1], q);
  float d = dis[node];
  float4 bb = ((const float4*)b1)[q];
  float4 z;
  z.x = d * fmaxf(fmaf(d, a.x, bb.x), 0.f);
  z.y = d * fmaxf(fmaf(d, a.y, bb.y), 0.f);
  z.z = d * fmaxf(fmaf(d, a.z, bb.z), 0.f);
  z.w = d * fmaxf(fmaf(d, a.w, bb.w), 0.f);
  ((ushort4*)zb)[(size_t)node * 4 + q] = pk4(z);
}

// aggregate + final epilogue (bf16 in, W2 matmul + log_softmax, f32 out)
__global__ __launch_bounds__(256) void k_aggF(
    const int* __restrict__ rowptr, const int2* __restrict__ csr,
    const unsigned short* __restrict__ vals, float* __restrict__ out,
    const float* __restrict__ dis, const float* __restrict__ W2,
    const float* __restrict__ b2, int N) {
  __shared__ float w2s[HDIM * CODIM + CODIM];
  int t = threadIdx.x;
  for (int i = t; i < HDIM * CODIM; i += 256) w2s[i] = W2[i];
  if (t < CODIM) w2s[HDIM * CODIM + t] = b2[t];
  __syncthreads();

  int node = blockIdx.x * 64 + (t >> 2);
  int q = t & 3;
  if (node >= N) return;
  const ushort4* v4 = (const ushort4*)vals;
  float4 a = rowAccB(csr, v4, bf4(v4[(size_t)node * 4 + q]),
                     rowptr[node], rowptr[node + 1], q);
  float d = dis[node];
  a.x *= d; a.y *= d; a.z *= d; a.w *= d;

  float4 f1 = shx4(a, 1), f2 = shx4(a, 2), f3 = shx4(a, 3);

  int col0 = q * 10;
  float v[10];
  #pragma unroll
  for (int jj = 0; jj < 10; ++jj) v[jj] = w2s[HDIM * CODIM + col0 + jj];

  {
    const float* wr;
    wr = w2s + ((q ^ 0) * 4 + 0) * CODIM + col0;
    #pragma unroll
    for (int jj = 0; jj < 10; ++jj) v[jj] = fmaf(a.x, wr[jj], v[jj]);
    wr = w2s + ((q ^ 0) * 4 + 1) * CODIM + col0;
    #pragma unroll
    for (int jj = 0; jj < 10; ++jj) v[jj] = fmaf(a.y, wr[jj], v[jj]);
    wr = w2s + ((q ^ 0) * 4 + 2) * CODIM + col0;
    #pragma unroll
    for (int jj = 0; jj < 10; ++jj) v[jj] = fmaf(a.z, wr[jj], v[jj]);
    wr = w2s + ((q ^ 0) * 4 + 3) * CODIM + col0;
    #pragma unroll
    for (int jj = 0; jj < 10; ++jj) v[jj] = fmaf(a.w, wr[jj], v[jj]);

    wr = w2s + ((q ^ 1) * 4 + 0) * CODIM + col0;
    #pragma unroll
    for (int jj = 0; jj < 10; ++jj) v[jj] = fmaf(f1.x, wr[jj], v[jj]);
    wr = w2s + ((q ^ 1) * 4 + 1) * CODIM + col0;
    #pragma unroll
    for (int jj = 0; jj < 10; ++jj) v[jj] = fmaf(f1.y, wr[jj], v[jj]);
    wr = w2s + ((q ^ 1) * 4 + 2) * CODIM + col0;
    #pragma unroll
    for (int jj = 0; jj < 10; ++jj) v[jj] = fmaf(f1.z, wr[jj], v[jj]);
    wr = w2s + ((q ^ 1) * 4 + 3) * CODIM + col0;
    #pragma unroll
    for (int jj = 0; jj < 10; ++jj) v[jj] = fmaf(f1.w, wr[jj], v[jj]);

    wr = w2s + ((q ^ 2) * 4 + 0) * CODIM + col0;
    #pragma unroll
    for (int jj = 0; jj < 10; ++jj) v[jj] = fmaf(f2.x, wr[jj], v[jj]);
    wr = w2s + ((q ^ 2) * 4 + 1) * CODIM + col0;
    #pragma unroll
    for (int jj = 0; jj < 10; ++jj) v[jj] = fmaf(f2.y, wr[jj], v[jj]);
    wr = w2s + ((q ^ 2) * 4 + 2) * CODIM + col0;
    #pragma unroll
    for (int jj = 0; jj < 10; ++jj) v[jj] = fmaf(f2.z, wr[jj], v[jj]);
    wr = w2s + ((q ^ 2) * 4 + 3) * CODIM + col0;
    #pragma unroll
    for (int jj = 0; jj < 10; ++jj) v[jj] = fmaf(f2.w, wr[jj], v[jj]);

    wr = w2s + ((q ^ 3) * 4 + 0) * CODIM + col0;
    #pragma unroll
    for (int jj = 0; jj < 10; ++jj) v[jj] = fmaf(f3.x, wr[jj], v[jj]);
    wr = w2s + ((q ^ 3) * 4 + 1) * CODIM + col0;
    #pragma unroll
    for (int jj = 0; jj < 10; ++jj) v[jj] = fmaf(f3.y, wr[jj], v[jj]);
    wr = w2s + ((q ^ 3) * 4 + 2) * CODIM + col0;
    #pragma unroll
    for (int jj = 0; jj < 10; ++jj) v[jj] = fmaf(f3.z, wr[jj], v[jj]);
    wr = w2s + ((q ^ 3) * 4 + 3) * CODIM + col0;
    #pragma unroll
    for (int jj = 0; jj < 10; ++jj) v[jj] = fmaf(f3.w, wr[jj], v[jj]);
  }

  float m = v[0];
  #pragma unroll
  for (int jj = 1; jj < 10; ++jj) m = fmaxf(m, v[jj]);
  m = fmaxf(m, __shfl_xor(m, 1));
  m = fmaxf(m, __shfl_xor(m, 2));
  float sum = 0.f;
  #pragma unroll
  for (int jj = 0; jj < 10; ++jj) sum += __expf(v[jj] - m);
  sum += __shfl_xor(sum, 1);
  sum += __shfl_xor(sum, 2);
  float lse = __logf(sum) + m;
  float* o = out + (size_t)node * CODIM + col0;
  #pragma unroll
  for (int jj = 0; jj < 10; ++jj) o[jj] = v[jj] - lse;
}

extern "C" void kernel_launch(void* const* d_in, const int* in_sizes, int n_in,
                              void* d_out, int out_size, void* d_ws, size_t ws_size,
                              hipStream_t stream) {
  const float* x  = (const float*)d_in[0];
  const int*   ei = (const int*)d_in[1];   // [2, E]: row0=src, row1=dst
  const float* ew = (const float*)d_in[2];
  const float* W1 = (const float*)d_in[3];
  const float* b1 = (const float*)d_in[4];
  const float* W2 = (const float*)d_in[5];
  const float* b2 = (const float*)d_in[6];
  float* out = (float*)d_out;

  int N = in_sizes[0] / CIN;
  int E = in_sizes[2];
  const int* src = ei;
  const int* dst = ei + E;
  int NB = (N + BINSZ - 1) >> BSHIFT;

  // ---- workspace layout (y1 aliases dead padded-binned region) ----
  size_t NA = ((size_t)N + 255) & ~(size_t)255;
  size_t NP = ((size_t)N + 2) & ~(size_t)1;
  int*   cursor = (int*)d_ws;                       // NBMAX (counts after binB)
  int*   binoff = cursor + NBMAX;                   // NBMAX+1 -> pad +4
  int*   rowptr = binoff + NBMAX + 4;               // NP
  int2*  csr    = (int2*)(rowptr + NP);             // E
  float* dis    = (float*)(csr + E);                // NA
  unsigned short* zb = (unsigned short*)(dis + NA); // NA*16 bf16 (z table)
  uint2* binned = (uint2*)(zb + NA * 16);           // NB*CAP (dead after k_csrbin)
  unsigned short* y1 = (unsigned short*)binned;     // NA*16 bf16 (aliases binned)

  int gG   = (N + 63) / 64;
  int gEB  = (E + EB - 1) / EB;

  k_zero    <<<(NB + 255) / 256, 256, 0, stream>>>(cursor, NB);
  k_binB    <<<gEB, 256, 0, stream>>>(src, dst, ew, cursor, binned, E);
  k_scanBins<<<1, 256, 0, stream>>>(cursor, binoff, rowptr, NB, N);
  k_csrbin  <<<NB, 1024, 0, stream>>>(binoff, binned, rowptr, csr, dis, N);

  k_gemm1   <<<gG, 256, 0, stream>>>(x, W1, dis, y1, N);
  k_aggZ    <<<gG, 256, 0, stream>>>(rowptr, csr, y1, zb, dis, b1, N);
  k_aggF    <<<gG, 256, 0, stream>>>(rowptr, csr, zb, out, dis, W2, b2, N);
}